// Round 3
// baseline (501.073 us; speedup 1.0000x reference)
//
#include <hip/hip_runtime.h>
#include <hip/hip_fp16.h>

#define N_NODES 100000
#define N_EDGES 1600000
#define ELL_W 64
#define SEG 12500     // nodes per out_deg histogram segment (8 segments)
#define NSEG 8
#define NCHUNK 4      // edge chunks for out_deg histogram

// LDS-privatized histogram of src -> out_deg. Replaces 1.6M global atomics
// with ~393k merge atomics (R2 post-mortem: per-edge atomics each cost a
// ~48B EA transaction; atomic COUNT is the lever, not locality).
__global__ __launch_bounds__(512) void k_outdeg(const int* __restrict__ src, int* __restrict__ out_deg) {
    __shared__ int cnt[SEG];
    const int seg = blockIdx.y;
    const int lo = seg * SEG;
    for (int i = threadIdx.x; i < SEG; i += 512) cnt[i] = 0;
    __syncthreads();
    const int per4 = (N_EDGES / NCHUNK) / 4;           // int4 elements per chunk
    const int4* s4 = (const int4*)(src + blockIdx.x * (N_EDGES / NCHUNK));
    for (int i = threadIdx.x; i < per4; i += 512) {
        int4 v = s4[i];
        unsigned a = (unsigned)(v.x - lo), b = (unsigned)(v.y - lo);
        unsigned c = (unsigned)(v.z - lo), d = (unsigned)(v.w - lo);
        if (a < SEG) atomicAdd(&cnt[a], 1);
        if (b < SEG) atomicAdd(&cnt[b], 1);
        if (c < SEG) atomicAdd(&cnt[c], 1);
        if (d < SEG) atomicAdd(&cnt[d], 1);
    }
    __syncthreads();
    for (int i = threadIdx.x; i < SEG; i += 512) {
        int c = cnt[i];
        if (c) atomicAdd(&out_deg[lo + i], c);
    }
}

// Build transposed ELL adjacency (ell[slot * N_NODES + dst] = src) + in-degree (fill).
// Only the slot-assignment atomic remains (needs the returned value for uniqueness).
__global__ __launch_bounds__(256) void k_build(const int* __restrict__ src, const int* __restrict__ dst,
                                               int* __restrict__ fill, int* __restrict__ ell) {
    int e = blockIdx.x * 256 + threadIdx.x;
    if (e >= N_EDGES) return;
    int s = src[e];
    int d = dst[e];
    int p = atomicAdd(&fill[d], 1);
    if (p < ELL_W) ell[p * N_NODES + d] = s;
}

__global__ __launch_bounds__(256) void k_norm(const int* __restrict__ out_deg, const int* __restrict__ fill,
                                              float* __restrict__ norm_src, float* __restrict__ norm_dst) {
    int i = blockIdx.x * 256 + threadIdx.x;
    if (i >= N_NODES) return;
    int od = out_deg[i]; if (od < 1) od = 1;
    int id = fill[i];    if (id < 1) id = 1;
    norm_src[i] = rsqrtf((float)od);
    norm_dst[i] = rsqrtf((float)id);
}

// Y[r][c] = norm[r] * sum_k X[r][k] * W[k][c]; optional fp16 output (halves gather traffic).
template<int K, int NCOL, bool HALF_OUT>
__global__ __launch_bounds__(256) void k_gemm(const float* __restrict__ X, const float* __restrict__ W,
                                              const float* __restrict__ norm, void* __restrict__ Yv) {
    __shared__ float Xt[K][64];
    __shared__ float Wl[K][64];
    const int tid = threadIdx.x;
    const int row0 = blockIdx.x * 64;

    for (int idx = tid; idx < K * 64; idx += 256) {
        int k = idx >> 6, c = idx & 63;
        Wl[k][c] = (c < NCOL) ? W[k * NCOL + c] : 0.0f;
    }
    {
        int r = tid & 63;
        int gr = row0 + r;
        for (int kq = tid >> 6; kq < K / 4; kq += 4) {
            float4 v = make_float4(0.f, 0.f, 0.f, 0.f);
            if (gr < N_NODES) v = *(const float4*)(X + (long)gr * K + kq * 4);
            Xt[kq * 4 + 0][r] = v.x;
            Xt[kq * 4 + 1][r] = v.y;
            Xt[kq * 4 + 2][r] = v.z;
            Xt[kq * 4 + 3][r] = v.w;
        }
    }
    __syncthreads();

    const int rb = (tid >> 4) << 2;
    const int cb = (tid & 15) << 2;
    float acc[4][4] = {};
    #pragma unroll 4
    for (int k = 0; k < K; ++k) {
        float4 x4 = *(const float4*)&Xt[k][rb];
        float4 w4 = *(const float4*)&Wl[k][cb];
        float xv[4] = {x4.x, x4.y, x4.z, x4.w};
        float wv[4] = {w4.x, w4.y, w4.z, w4.w};
        #pragma unroll
        for (int i = 0; i < 4; ++i)
            #pragma unroll
            for (int j = 0; j < 4; ++j)
                acc[i][j] += xv[i] * wv[j];
    }

    if (cb < NCOL) {
        #pragma unroll
        for (int i = 0; i < 4; ++i) {
            int gr = row0 + rb + i;
            if (gr < N_NODES) {
                float s = norm[gr];
                float o0 = acc[i][0] * s, o1 = acc[i][1] * s, o2 = acc[i][2] * s, o3 = acc[i][3] * s;
                if (HALF_OUT) {
                    __half* Y = (__half*)Yv;
                    ushort4 pk;
                    pk.x = __half_as_ushort(__float2half(o0));
                    pk.y = __half_as_ushort(__float2half(o1));
                    pk.z = __half_as_ushort(__float2half(o2));
                    pk.w = __half_as_ushort(__float2half(o3));
                    *(ushort4*)(Y + (long)gr * NCOL + cb) = pk;
                } else {
                    float* Y = (float*)Yv;
                    *(float4*)(Y + (long)gr * NCOL + cb) = make_float4(o0, o1, o2, o3);
                }
            }
        }
    }
}

// OUT[d][:] = act( norm_dst[d] * sum_{s in ell[d]} XW[s][:] + bias )
// One thread per (node, 4-feat quad); gather unrolled x4 for MLP.
template<int NF, bool RELU, bool HALF_IN>
__global__ __launch_bounds__(256) void k_agg(const void* __restrict__ XWv, const int* __restrict__ ell,
                                             const int* __restrict__ deg, const float* __restrict__ norm_dst,
                                             const float* __restrict__ bias, float* __restrict__ OUT) {
    constexpr int NQ = NF / 4;
    int gid = blockIdx.x * 256 + threadIdx.x;
    int d = gid / NQ;
    int q = gid - d * NQ;
    if (d >= N_NODES) return;
    int dg = deg[d]; if (dg > ELL_W) dg = ELL_W;

    const __half* XWh = (const __half*)XWv;
    const float* XWf = (const float*)XWv;

    float a0 = 0.f, a1 = 0.f, a2 = 0.f, a3 = 0.f;
    int j = 0;
    for (; j + 4 <= dg; j += 4) {
        int i0 = ell[(j + 0) * N_NODES + d];
        int i1 = ell[(j + 1) * N_NODES + d];
        int i2 = ell[(j + 2) * N_NODES + d];
        int i3 = ell[(j + 3) * N_NODES + d];
        if (HALF_IN) {
            float2 r0 = *(const float2*)(XWh + (long)i0 * NF + q * 4);
            float2 r1 = *(const float2*)(XWh + (long)i1 * NF + q * 4);
            float2 r2 = *(const float2*)(XWh + (long)i2 * NF + q * 4);
            float2 r3 = *(const float2*)(XWh + (long)i3 * NF + q * 4);
            float2 p0a = __half22float2(*(__half2*)&r0.x), p0b = __half22float2(*(__half2*)&r0.y);
            float2 p1a = __half22float2(*(__half2*)&r1.x), p1b = __half22float2(*(__half2*)&r1.y);
            float2 p2a = __half22float2(*(__half2*)&r2.x), p2b = __half22float2(*(__half2*)&r2.y);
            float2 p3a = __half22float2(*(__half2*)&r3.x), p3b = __half22float2(*(__half2*)&r3.y);
            a0 += p0a.x + p1a.x + p2a.x + p3a.x;
            a1 += p0a.y + p1a.y + p2a.y + p3a.y;
            a2 += p0b.x + p1b.x + p2b.x + p3b.x;
            a3 += p0b.y + p1b.y + p2b.y + p3b.y;
        } else {
            float4 v0 = *(const float4*)(XWf + (long)i0 * NF + q * 4);
            float4 v1 = *(const float4*)(XWf + (long)i1 * NF + q * 4);
            float4 v2 = *(const float4*)(XWf + (long)i2 * NF + q * 4);
            float4 v3 = *(const float4*)(XWf + (long)i3 * NF + q * 4);
            a0 += v0.x + v1.x + v2.x + v3.x;
            a1 += v0.y + v1.y + v2.y + v3.y;
            a2 += v0.z + v1.z + v2.z + v3.z;
            a3 += v0.w + v1.w + v2.w + v3.w;
        }
    }
    for (; j < dg; ++j) {
        int s = ell[j * N_NODES + d];
        if (HALF_IN) {
            float2 r = *(const float2*)(XWh + (long)s * NF + q * 4);
            float2 pa = __half22float2(*(__half2*)&r.x), pb = __half22float2(*(__half2*)&r.y);
            a0 += pa.x; a1 += pa.y; a2 += pb.x; a3 += pb.y;
        } else {
            float4 v = *(const float4*)(XWf + (long)s * NF + q * 4);
            a0 += v.x; a1 += v.y; a2 += v.z; a3 += v.w;
        }
    }

    float nd = norm_dst[d];
    float o0 = a0 * nd + bias[q * 4 + 0];
    float o1 = a1 * nd + bias[q * 4 + 1];
    float o2 = a2 * nd + bias[q * 4 + 2];
    float o3 = a3 * nd + bias[q * 4 + 3];
    if (RELU) {
        o0 = fmaxf(o0, 0.f); o1 = fmaxf(o1, 0.f);
        o2 = fmaxf(o2, 0.f); o3 = fmaxf(o3, 0.f);
    }
    *(float4*)(OUT + (long)d * NF + q * 4) = make_float4(o0, o1, o2, o3);
}

extern "C" void kernel_launch(void* const* d_in, const int* in_sizes, int n_in,
                              void* d_out, int out_size, void* d_ws, size_t ws_size,
                              hipStream_t stream) {
    const float* h  = (const float*)d_in[0];
    const float* W0 = (const float*)d_in[1];
    const float* b0 = (const float*)d_in[2];
    const float* W1 = (const float*)d_in[3];
    const float* b1 = (const float*)d_in[4];
    const float* W2 = (const float*)d_in[5];
    const float* b2 = (const float*)d_in[6];
    const int* src  = (const int*)d_in[7];
    const int* dst  = (const int*)d_in[8];
    float* out = (float*)d_out;

    char* ws = (char*)d_ws;
    size_t off = 0;
    int* fill        = (int*)(ws + off); off += (size_t)N_NODES * 4;        // in_deg
    int* out_deg     = (int*)(ws + off); off += (size_t)N_NODES * 4;
    float* norm_src  = (float*)(ws + off); off += (size_t)N_NODES * 4;
    float* norm_dst  = (float*)(ws + off); off += (size_t)N_NODES * 4;
    int* ell         = (int*)(ws + off); off += (size_t)N_NODES * ELL_W * 4;  // [ELL_W][N_NODES]
    float* bufA      = (float*)(ws + off); off += (size_t)N_NODES * 64 * 4;   // fp32 or fp16 views
    float* bufB      = (float*)(ws + off); off += (size_t)N_NODES * 64 * 4;

    hipMemsetAsync(fill, 0, (size_t)N_NODES * 8, stream);   // clears fill + out_deg

    k_outdeg<<<dim3(NCHUNK, NSEG), 512, 0, stream>>>(src, out_deg);
    k_build<<<(N_EDGES + 255) / 256, 256, 0, stream>>>(src, dst, fill, ell);
    k_norm<<<(N_NODES + 255) / 256, 256, 0, stream>>>(out_deg, fill, norm_src, norm_dst);

    // Layer 0: fp16 intermediate for the gather
    k_gemm<128, 64, true><<<(N_NODES + 63) / 64, 256, 0, stream>>>(h, W0, norm_src, bufA);
    k_agg<64, true, true><<<(N_NODES * 16 + 255) / 256, 256, 0, stream>>>(bufA, ell, fill, norm_dst, b0, bufB);

    // Layer 1: fp16 intermediate
    k_gemm<64, 64, true><<<(N_NODES + 63) / 64, 256, 0, stream>>>(bufB, W1, norm_src, bufA);
    k_agg<64, true, true><<<(N_NODES * 16 + 255) / 256, 256, 0, stream>>>(bufA, ell, fill, norm_dst, b1, bufB);

    // Layer 2: fp32 (final accuracy)
    k_gemm<64, 40, false><<<(N_NODES + 63) / 64, 256, 0, stream>>>(bufB, W2, norm_src, bufA);
    k_agg<40, false, false><<<(N_NODES * 10 + 255) / 256, 256, 0, stream>>>(bufA, ell, fill, norm_dst, b2, out);
}

// Round 4
// 358.323 us; speedup vs baseline: 1.3984x; 1.3984x over previous
//
#include <hip/hip_runtime.h>
#include <hip/hip_fp16.h>

#define N_NODES 100000
#define N_EDGES 1600000
#define ELL_W 64
#define NCHUNK 32                  // edge chunks
#define NSEG 8                     // node segments
#define CH (N_EDGES / NCHUNK)      // 50000 edges per chunk
#define SEGN (N_NODES / NSEG)      // 12500 nodes per segment

// Pass A: per-(chunk,segment) LDS histograms of src (out-deg) and dst (in-deg).
// Each block OWNS its output slice -> plain stores, zero global atomics, no memset.
__global__ __launch_bounds__(512) void k_count(const int* __restrict__ src, const int* __restrict__ dst,
                                               int* __restrict__ cnt_out, int* __restrict__ cnt_in) {
    __shared__ int ci[SEGN];
    __shared__ int co[SEGN];
    const int c = blockIdx.x;
    const int lo = blockIdx.y * SEGN;
    for (int i = threadIdx.x; i < SEGN; i += 512) { ci[i] = 0; co[i] = 0; }
    __syncthreads();
    const int4* s4 = (const int4*)(src + c * CH);
    const int4* d4 = (const int4*)(dst + c * CH);
    for (int i = threadIdx.x; i < CH / 4; i += 512) {
        int4 s = s4[i], d = d4[i];
        unsigned a;
        a = (unsigned)(s.x - lo); if (a < SEGN) atomicAdd(&co[a], 1);
        a = (unsigned)(s.y - lo); if (a < SEGN) atomicAdd(&co[a], 1);
        a = (unsigned)(s.z - lo); if (a < SEGN) atomicAdd(&co[a], 1);
        a = (unsigned)(s.w - lo); if (a < SEGN) atomicAdd(&co[a], 1);
        a = (unsigned)(d.x - lo); if (a < SEGN) atomicAdd(&ci[a], 1);
        a = (unsigned)(d.y - lo); if (a < SEGN) atomicAdd(&ci[a], 1);
        a = (unsigned)(d.z - lo); if (a < SEGN) atomicAdd(&ci[a], 1);
        a = (unsigned)(d.w - lo); if (a < SEGN) atomicAdd(&ci[a], 1);
    }
    __syncthreads();
    for (int i = threadIdx.x; i < SEGN; i += 512) {
        cnt_in [c * N_NODES + lo + i] = ci[i];
        cnt_out[c * N_NODES + lo + i] = co[i];
    }
}

// Pass B: exclusive prefix over chunks per dst (in place: counts -> bases),
// plus in_deg / norm_src / norm_dst (absorbs old k_norm + k_outdeg merge).
__global__ __launch_bounds__(256) void k_scan(int* __restrict__ cnt_in, const int* __restrict__ cnt_out,
                                              int* __restrict__ fill, float* __restrict__ norm_src,
                                              float* __restrict__ norm_dst) {
    int d = blockIdx.x * 256 + threadIdx.x;
    if (d >= N_NODES) return;
    int run = 0;
    #pragma unroll
    for (int c = 0; c < NCHUNK; ++c) {
        int v = cnt_in[c * N_NODES + d];
        cnt_in[c * N_NODES + d] = run;
        run += v;
    }
    int od = 0;
    #pragma unroll
    for (int c = 0; c < NCHUNK; ++c) od += cnt_out[c * N_NODES + d];
    fill[d] = run;
    norm_dst[d] = rsqrtf((float)(run < 1 ? 1 : run));
    norm_src[d] = rsqrtf((float)(od  < 1 ? 1 : od ));
}

// Pass C: slot assignment via LDS atomics only; write transposed ELL.
__global__ __launch_bounds__(512) void k_scatter(const int* __restrict__ src, const int* __restrict__ dst,
                                                 const int* __restrict__ bases, int* __restrict__ ell) {
    __shared__ int base[SEGN];
    const int c = blockIdx.x;
    const int lo = blockIdx.y * SEGN;
    for (int i = threadIdx.x; i < SEGN; i += 512) base[i] = bases[c * N_NODES + lo + i];
    __syncthreads();
    const int4* s4 = (const int4*)(src + c * CH);
    const int4* d4 = (const int4*)(dst + c * CH);
    for (int i = threadIdx.x; i < CH / 4; i += 512) {
        int4 s = s4[i], d = d4[i];
        unsigned r; int p;
        r = (unsigned)(d.x - lo); if (r < SEGN) { p = atomicAdd(&base[r], 1); if (p < ELL_W) ell[p * N_NODES + lo + r] = s.x; }
        r = (unsigned)(d.y - lo); if (r < SEGN) { p = atomicAdd(&base[r], 1); if (p < ELL_W) ell[p * N_NODES + lo + r] = s.y; }
        r = (unsigned)(d.z - lo); if (r < SEGN) { p = atomicAdd(&base[r], 1); if (p < ELL_W) ell[p * N_NODES + lo + r] = s.z; }
        r = (unsigned)(d.w - lo); if (r < SEGN) { p = atomicAdd(&base[r], 1); if (p < ELL_W) ell[p * N_NODES + lo + r] = s.w; }
    }
}

// Y[r][c] = norm[r] * sum_k X[r][k] * W[k][c]; optional fp16 output (halves gather traffic).
template<int K, int NCOL, bool HALF_OUT>
__global__ __launch_bounds__(256) void k_gemm(const float* __restrict__ X, const float* __restrict__ W,
                                              const float* __restrict__ norm, void* __restrict__ Yv) {
    __shared__ float Xt[K][64];
    __shared__ float Wl[K][64];
    const int tid = threadIdx.x;
    const int row0 = blockIdx.x * 64;

    for (int idx = tid; idx < K * 64; idx += 256) {
        int k = idx >> 6, c = idx & 63;
        Wl[k][c] = (c < NCOL) ? W[k * NCOL + c] : 0.0f;
    }
    {
        int r = tid & 63;
        int gr = row0 + r;
        for (int kq = tid >> 6; kq < K / 4; kq += 4) {
            float4 v = make_float4(0.f, 0.f, 0.f, 0.f);
            if (gr < N_NODES) v = *(const float4*)(X + (long)gr * K + kq * 4);
            Xt[kq * 4 + 0][r] = v.x;
            Xt[kq * 4 + 1][r] = v.y;
            Xt[kq * 4 + 2][r] = v.z;
            Xt[kq * 4 + 3][r] = v.w;
        }
    }
    __syncthreads();

    const int rb = (tid >> 4) << 2;
    const int cb = (tid & 15) << 2;
    float acc[4][4] = {};
    #pragma unroll 4
    for (int k = 0; k < K; ++k) {
        float4 x4 = *(const float4*)&Xt[k][rb];
        float4 w4 = *(const float4*)&Wl[k][cb];
        float xv[4] = {x4.x, x4.y, x4.z, x4.w};
        float wv[4] = {w4.x, w4.y, w4.z, w4.w};
        #pragma unroll
        for (int i = 0; i < 4; ++i)
            #pragma unroll
            for (int j = 0; j < 4; ++j)
                acc[i][j] += xv[i] * wv[j];
    }

    if (cb < NCOL) {
        #pragma unroll
        for (int i = 0; i < 4; ++i) {
            int gr = row0 + rb + i;
            if (gr < N_NODES) {
                float s = norm[gr];
                float o0 = acc[i][0] * s, o1 = acc[i][1] * s, o2 = acc[i][2] * s, o3 = acc[i][3] * s;
                if (HALF_OUT) {
                    __half* Y = (__half*)Yv;
                    ushort4 pk;
                    pk.x = __half_as_ushort(__float2half(o0));
                    pk.y = __half_as_ushort(__float2half(o1));
                    pk.z = __half_as_ushort(__float2half(o2));
                    pk.w = __half_as_ushort(__float2half(o3));
                    *(ushort4*)(Y + (long)gr * NCOL + cb) = pk;
                } else {
                    float* Y = (float*)Yv;
                    *(float4*)(Y + (long)gr * NCOL + cb) = make_float4(o0, o1, o2, o3);
                }
            }
        }
    }
}

// OUT[d][:] = act( norm_dst[d] * sum_{s in ell[d]} XW[s][:] + bias )
// One thread per (node, 4-feat quad); gather unrolled x4 for MLP.
template<int NF, bool RELU, bool HALF_IN>
__global__ __launch_bounds__(256) void k_agg(const void* __restrict__ XWv, const int* __restrict__ ell,
                                             const int* __restrict__ deg, const float* __restrict__ norm_dst,
                                             const float* __restrict__ bias, float* __restrict__ OUT) {
    constexpr int NQ = NF / 4;
    int gid = blockIdx.x * 256 + threadIdx.x;
    int d = gid / NQ;
    int q = gid - d * NQ;
    if (d >= N_NODES) return;
    int dg = deg[d]; if (dg > ELL_W) dg = ELL_W;

    const __half* XWh = (const __half*)XWv;
    const float* XWf = (const float*)XWv;

    float a0 = 0.f, a1 = 0.f, a2 = 0.f, a3 = 0.f;
    int j = 0;
    for (; j + 4 <= dg; j += 4) {
        int i0 = ell[(j + 0) * N_NODES + d];
        int i1 = ell[(j + 1) * N_NODES + d];
        int i2 = ell[(j + 2) * N_NODES + d];
        int i3 = ell[(j + 3) * N_NODES + d];
        if (HALF_IN) {
            float2 r0 = *(const float2*)(XWh + (long)i0 * NF + q * 4);
            float2 r1 = *(const float2*)(XWh + (long)i1 * NF + q * 4);
            float2 r2 = *(const float2*)(XWh + (long)i2 * NF + q * 4);
            float2 r3 = *(const float2*)(XWh + (long)i3 * NF + q * 4);
            float2 p0a = __half22float2(*(__half2*)&r0.x), p0b = __half22float2(*(__half2*)&r0.y);
            float2 p1a = __half22float2(*(__half2*)&r1.x), p1b = __half22float2(*(__half2*)&r1.y);
            float2 p2a = __half22float2(*(__half2*)&r2.x), p2b = __half22float2(*(__half2*)&r2.y);
            float2 p3a = __half22float2(*(__half2*)&r3.x), p3b = __half22float2(*(__half2*)&r3.y);
            a0 += p0a.x + p1a.x + p2a.x + p3a.x;
            a1 += p0a.y + p1a.y + p2a.y + p3a.y;
            a2 += p0b.x + p1b.x + p2b.x + p3b.x;
            a3 += p0b.y + p1b.y + p2b.y + p3b.y;
        } else {
            float4 v0 = *(const float4*)(XWf + (long)i0 * NF + q * 4);
            float4 v1 = *(const float4*)(XWf + (long)i1 * NF + q * 4);
            float4 v2 = *(const float4*)(XWf + (long)i2 * NF + q * 4);
            float4 v3 = *(const float4*)(XWf + (long)i3 * NF + q * 4);
            a0 += v0.x + v1.x + v2.x + v3.x;
            a1 += v0.y + v1.y + v2.y + v3.y;
            a2 += v0.z + v1.z + v2.z + v3.z;
            a3 += v0.w + v1.w + v2.w + v3.w;
        }
    }
    for (; j < dg; ++j) {
        int s = ell[j * N_NODES + d];
        if (HALF_IN) {
            float2 r = *(const float2*)(XWh + (long)s * NF + q * 4);
            float2 pa = __half22float2(*(__half2*)&r.x), pb = __half22float2(*(__half2*)&r.y);
            a0 += pa.x; a1 += pa.y; a2 += pb.x; a3 += pb.y;
        } else {
            float4 v = *(const float4*)(XWf + (long)s * NF + q * 4);
            a0 += v.x; a1 += v.y; a2 += v.z; a3 += v.w;
        }
    }

    float nd = norm_dst[d];
    float o0 = a0 * nd + bias[q * 4 + 0];
    float o1 = a1 * nd + bias[q * 4 + 1];
    float o2 = a2 * nd + bias[q * 4 + 2];
    float o3 = a3 * nd + bias[q * 4 + 3];
    if (RELU) {
        o0 = fmaxf(o0, 0.f); o1 = fmaxf(o1, 0.f);
        o2 = fmaxf(o2, 0.f); o3 = fmaxf(o3, 0.f);
    }
    *(float4*)(OUT + (long)d * NF + q * 4) = make_float4(o0, o1, o2, o3);
}

extern "C" void kernel_launch(void* const* d_in, const int* in_sizes, int n_in,
                              void* d_out, int out_size, void* d_ws, size_t ws_size,
                              hipStream_t stream) {
    const float* h  = (const float*)d_in[0];
    const float* W0 = (const float*)d_in[1];
    const float* b0 = (const float*)d_in[2];
    const float* W1 = (const float*)d_in[3];
    const float* b1 = (const float*)d_in[4];
    const float* W2 = (const float*)d_in[5];
    const float* b2 = (const float*)d_in[6];
    const int* src  = (const int*)d_in[7];
    const int* dst  = (const int*)d_in[8];
    float* out = (float*)d_out;

    char* ws = (char*)d_ws;
    size_t off = 0;
    int* fill        = (int*)(ws + off); off += (size_t)N_NODES * 4;   // in_deg
    float* norm_src  = (float*)(ws + off); off += (size_t)N_NODES * 4;
    float* norm_dst  = (float*)(ws + off); off += (size_t)N_NODES * 4;
    int* ell         = (int*)(ws + off); off += (size_t)N_NODES * ELL_W * 4;   // [ELL_W][N_NODES]
    // Overlay: cnt_in/cnt_out (build phase) share memory with bufA/bufB
    // (layer phase) — cnt arrays are dead after k_scatter, bufs born after.
    char* big = ws + off;
    int* cnt_in  = (int*)(big);                                        // 12.8 MB (becomes bases)
    int* cnt_out = (int*)(big + (size_t)NCHUNK * N_NODES * 4);         // 12.8 MB
    float* bufA  = (float*)(big);                                      // 16 MB max (fp16 64w / fp32 40w)
    float* bufB  = (float*)(big + (size_t)N_NODES * 40 * 4);           // 25.6 MB (fp32 64w)

    // Build (zero global atomics):
    k_count<<<dim3(NCHUNK, NSEG), 512, 0, stream>>>(src, dst, cnt_out, cnt_in);
    k_scan<<<(N_NODES + 255) / 256, 256, 0, stream>>>(cnt_in, cnt_out, fill, norm_src, norm_dst);
    k_scatter<<<dim3(NCHUNK, NSEG), 512, 0, stream>>>(src, dst, cnt_in, ell);

    // Layer 0: fp16 intermediate for the gather
    k_gemm<128, 64, true><<<(N_NODES + 63) / 64, 256, 0, stream>>>(h, W0, norm_src, bufA);
    k_agg<64, true, true><<<(N_NODES * 16 + 255) / 256, 256, 0, stream>>>(bufA, ell, fill, norm_dst, b0, bufB);

    // Layer 1: fp16 intermediate
    k_gemm<64, 64, true><<<(N_NODES + 63) / 64, 256, 0, stream>>>(bufB, W1, norm_src, bufA);
    k_agg<64, true, true><<<(N_NODES * 16 + 255) / 256, 256, 0, stream>>>(bufA, ell, fill, norm_dst, b1, bufB);

    // Layer 2: fp32 (final accuracy)
    k_gemm<64, 40, false><<<(N_NODES + 63) / 64, 256, 0, stream>>>(bufB, W2, norm_src, bufA);
    k_agg<40, false, false><<<(N_NODES * 10 + 255) / 256, 256, 0, stream>>>(bufA, ell, fill, norm_dst, b2, out);
}